// Round 1
// baseline (622.998 us; speedup 1.0000x reference)
//
#include <hip/hip_runtime.h>

// Shapes (fixed by the problem)
// B=4, D=8, H=14, W=14, C=768, NH=12, hd=64, N=1568, BH=48, M=6272, 3C=2304

typedef __bf16 bf16x8 __attribute__((ext_vector_type(8)));
typedef float f32x4 __attribute__((ext_vector_type(4)));

static __device__ __forceinline__ unsigned short f2bf(float f) {
    union { float f; unsigned int u; } v; v.f = f;
    unsigned int u = v.u;
    return (unsigned short)((u + 0x7fffu + ((u >> 16) & 1u)) >> 16);
}

static __device__ __forceinline__ bf16x8 ld_bf8(const unsigned short* p) {
    return *reinterpret_cast<const bf16x8*>(p);
}
static __device__ __forceinline__ bf16x8 ld_bf8_lds(const unsigned short* p) {
    return *reinterpret_cast<const bf16x8*>(p);
}

// ---------------- prep kernels ----------------

__global__ void k_cvt_x(const float* __restrict__ x, unsigned short* __restrict__ xbf, int n4) {
    int i = blockIdx.x * blockDim.x + threadIdx.x;
    if (i < n4) {
        float4 v = reinterpret_cast<const float4*>(x)[i];
        ushort4 o;
        o.x = f2bf(v.x); o.y = f2bf(v.y); o.z = f2bf(v.z); o.w = f2bf(v.w);
        reinterpret_cast<ushort4*>(xbf)[i] = o;
    }
}

// w [K][N] fp32 -> wt [N][K] bf16 ; K,N multiples of 64
__global__ __launch_bounds__(256) void k_transpose(const float* __restrict__ w,
                                                   unsigned short* __restrict__ wt,
                                                   int K, int N) {
    __shared__ float tile[64][65];
    int kt = blockIdx.x * 64;
    int nt = blockIdx.y * 64;
    int tid = threadIdx.x;
    int r = tid >> 2;      // 0..63
    int cg = tid & 3;      // 0..3
#pragma unroll
    for (int i = 0; i < 4; ++i) {
        int c = cg * 16 + i * 4;
        float4 v = *reinterpret_cast<const float4*>(&w[(size_t)(kt + r) * N + nt + c]);
        tile[r][c + 0] = v.x; tile[r][c + 1] = v.y; tile[r][c + 2] = v.z; tile[r][c + 3] = v.w;
    }
    __syncthreads();
#pragma unroll
    for (int i = 0; i < 4; ++i) {
        int c = cg * 16 + i * 4;
        ushort4 o;
        o.x = f2bf(tile[c + 0][r]);
        o.y = f2bf(tile[c + 1][r]);
        o.z = f2bf(tile[c + 2][r]);
        o.w = f2bf(tile[c + 3][r]);
        *reinterpret_cast<ushort4*>(&wt[(size_t)(nt + r) * K + kt + c]) = o;
    }
}

// concat rel_pos_d (15 rows) | rel_pos_h (27) | rel_pos_w (27) -> T[80][64] bf16 (rows 69..79 zero)
__global__ void k_tables(const float* __restrict__ rd, const float* __restrict__ rh,
                         const float* __restrict__ rw, unsigned short* __restrict__ T) {
    int i = blockIdx.x * blockDim.x + threadIdx.x;
    if (i < 80 * 64) {
        int row = i >> 6, c = i & 63;
        float v = 0.f;
        if (row < 15) v = rd[row * 64 + c];
        else if (row < 42) v = rh[(row - 15) * 64 + c];
        else if (row < 69) v = rw[(row - 42) * 64 + c];
        T[i] = f2bf(v);
    }
}

// ---------------- GEMM1: qkv = x @ qkv_w + b -> q,k,vT bf16 buffers ----------------
// x_bf [6272][768], w1t [2304][768] (transposed), out scattered:
//   q [bh][n][64], k [bh][n][64], vT [bh][64][1568]
__global__ __launch_bounds__(256) void k_qkv(const unsigned short* __restrict__ xbf,
                                             const unsigned short* __restrict__ w1t,
                                             const float* __restrict__ qkv_b,
                                             unsigned short* __restrict__ qb,
                                             unsigned short* __restrict__ kb,
                                             unsigned short* __restrict__ vtb) {
    int lane = threadIdx.x & 63;
    int wid = threadIdx.x >> 6;
    int quad = lane >> 4;
    int l16 = lane & 15;
    int mbase = blockIdx.x * 64 + wid * 16;
    int nbase = blockIdx.y * 64;
    f32x4 acc[4] = {};
    const unsigned short* arow = xbf + (size_t)(mbase + l16) * 768 + quad * 8;
    const unsigned short* brow = w1t + (size_t)(nbase + l16) * 768 + quad * 8;
    for (int ks = 0; ks < 24; ++ks) {
        bf16x8 a = ld_bf8(arow + ks * 32);
#pragma unroll
        for (int ng = 0; ng < 4; ++ng) {
            bf16x8 b = ld_bf8(brow + (size_t)ng * 16 * 768 + ks * 32);
            acc[ng] = __builtin_amdgcn_mfma_f32_16x16x32_bf16(a, b, acc[ng], 0, 0, 0);
        }
    }
#pragma unroll
    for (int ng = 0; ng < 4; ++ng) {
        int n = nbase + ng * 16 + l16;
        float bias = qkv_b[n];
        int which = n / 768;
        int rem = n - which * 768;
        int head = rem >> 6;
        int c = rem & 63;
#pragma unroll
        for (int r = 0; r < 4; ++r) {
            int m = mbase + quad * 4 + r;
            float val = acc[ng][r] + bias;
            int b_ = m / 1568;
            int nn = m - b_ * 1568;
            int bh = b_ * 12 + head;
            unsigned short bv = f2bf(val);
            if (which == 0)      qb[((size_t)bh * 1568 + nn) * 64 + c] = bv;
            else if (which == 1) kb[((size_t)bh * 1568 + nn) * 64 + c] = bv;
            else                 vtb[((size_t)bh * 64 + c) * 1568 + nn] = bv;
        }
    }
}

// ---------------- attention: flash-style with decomposed rel-pos bias ----------------
// grid (25 qtiles, 48 bh), block 256 (4 waves x 16 q rows)
__global__ __launch_bounds__(256) void k_attn(const unsigned short* __restrict__ qb,
                                              const unsigned short* __restrict__ kb,
                                              const unsigned short* __restrict__ vtb,
                                              const unsigned short* __restrict__ Tbf,
                                              unsigned short* __restrict__ obf) {
    __shared__ float qR[64][80];
    __shared__ __align__(16) unsigned short pP[4][1024];
    const int lane = threadIdx.x & 63;
    const int wid = threadIdx.x >> 6;
    const int quad = lane >> 4;
    const int l16 = lane & 15;
    const int qt = blockIdx.x;
    const int bh = blockIdx.y;
    const float scale = 0.125f;  // 64^-0.5

    // Q fragments (A-layout: m=l16, k=quad*8+j), clamped rows for the ragged last tile
    int qrow_l = qt * 64 + wid * 16 + l16;
    if (qrow_l > 1567) qrow_l = 1567;
    const unsigned short* qp = qb + ((size_t)bh * 1568 + qrow_l) * 64 + quad * 8;
    bf16x8 a_q0 = ld_bf8(qp);
    bf16x8 a_q1 = ld_bf8(qp + 32);

    // prologue: qR[q][j] = q . T_row_j  (j: 0..14 d-table, 15..41 h-table, 42..68 w-table)
#pragma unroll
    for (int ng = 0; ng < 5; ++ng) {
        const unsigned short* tp = Tbf + (size_t)(ng * 16 + l16) * 64 + quad * 8;
        bf16x8 b0 = ld_bf8(tp);
        bf16x8 b1 = ld_bf8(tp + 32);
        f32x4 t = {};
        t = __builtin_amdgcn_mfma_f32_16x16x32_bf16(a_q0, b0, t, 0, 0, 0);
        t = __builtin_amdgcn_mfma_f32_16x16x32_bf16(a_q1, b1, t, 0, 0, 0);
#pragma unroll
        for (int r = 0; r < 4; ++r)
            qR[wid * 16 + quad * 4 + r][ng * 16 + l16] = t[r];
    }
    __syncthreads();

    // per-lane query-row info for its 4 C-layout rows
    int lrow[4], rowd[4], rowh[4], roww[4];
#pragma unroll
    for (int r = 0; r < 4; ++r) {
        int lr = wid * 16 + quad * 4 + r;
        lrow[r] = lr;
        int gq = qt * 64 + lr;
        if (gq > 1567) gq = 1567;
        int d = gq / 196;
        int rm = gq - d * 196;
        int h = rm / 14;
        rowd[r] = d; rowh[r] = h; roww[r] = rm - h * 14;
    }

    float m_i[4], l_i[4];
    f32x4 Oacc[4] = {};
#pragma unroll
    for (int r = 0; r < 4; ++r) { m_i[r] = -1e30f; l_i[r] = 0.f; }

    const unsigned short* kbh = kb + (size_t)bh * 1568 * 64;
    const unsigned short* vbh = vtb + (size_t)bh * 64 * 1568;
    unsigned short* pw = pP[wid];

    for (int kt = 0; kt < 25; ++kt) {
        int kb0 = kt * 64;
        // ---- S = Q K^T ----
        f32x4 s[4];
#pragma unroll
        for (int kg = 0; kg < 4; ++kg) {
            int krow = kb0 + kg * 16 + l16;
            if (krow > 1567) krow = 1567;
            const unsigned short* kp = kbh + (size_t)krow * 64 + quad * 8;
            bf16x8 b0 = ld_bf8(kp);
            bf16x8 b1 = ld_bf8(kp + 32);
            f32x4 t = {};
            t = __builtin_amdgcn_mfma_f32_16x16x32_bf16(a_q0, b0, t, 0, 0, 0);
            t = __builtin_amdgcn_mfma_f32_16x16x32_bf16(a_q1, b1, t, 0, 0, 0);
            s[kg] = t;
        }
        // ---- scale + rel-pos bias + mask ----
        float p[4][4];
#pragma unroll
        for (int kg = 0; kg < 4; ++kg) {
            int key = kb0 + kg * 16 + l16;
            bool valid = key < 1568;
            int kd = key / 196;
            int krm = key - kd * 196;
            int kh = krm / 14;
            int kw = krm - kh * 14;
#pragma unroll
            for (int r = 0; r < 4; ++r) {
                float sv = s[kg][r] * scale
                         + qR[lrow[r]][rowd[r] - kd + 7]
                         + qR[lrow[r]][15 + rowh[r] - kh + 13]
                         + qR[lrow[r]][42 + roww[r] - kw + 13];
                p[kg][r] = valid ? sv : -1e30f;
            }
        }
        // ---- online softmax ----
        float alpha[4];
#pragma unroll
        for (int r = 0; r < 4; ++r) {
            float t = fmaxf(fmaxf(p[0][r], p[1][r]), fmaxf(p[2][r], p[3][r]));
            t = fmaxf(t, __shfl_xor(t, 1));
            t = fmaxf(t, __shfl_xor(t, 2));
            t = fmaxf(t, __shfl_xor(t, 4));
            t = fmaxf(t, __shfl_xor(t, 8));
            float mn = fmaxf(m_i[r], t);
            alpha[r] = __expf(m_i[r] - mn);
            float rs = 0.f;
#pragma unroll
            for (int kg = 0; kg < 4; ++kg) {
                float pv = __expf(p[kg][r] - mn);
                p[kg][r] = pv;
                rs += pv;
            }
            rs += __shfl_xor(rs, 1);
            rs += __shfl_xor(rs, 2);
            rs += __shfl_xor(rs, 4);
            rs += __shfl_xor(rs, 8);
            l_i[r] = l_i[r] * alpha[r] + rs;
            m_i[r] = mn;
        }
#pragma unroll
        for (int cg = 0; cg < 4; ++cg)
#pragma unroll
            for (int r = 0; r < 4; ++r)
                Oacc[cg][r] *= alpha[r];

        // ---- P: C-layout -> A-layout via wave-private LDS ----
#pragma unroll
        for (int kg = 0; kg < 4; ++kg)
#pragma unroll
            for (int r = 0; r < 4; ++r)
                pw[(quad * 4 + r) * 64 + kg * 16 + l16] = f2bf(p[kg][r]);
        __syncthreads();
        bf16x8 a_p0 = ld_bf8_lds(pw + l16 * 64 + quad * 8);
        bf16x8 a_p1 = ld_bf8_lds(pw + l16 * 64 + 32 + quad * 8);
        __syncthreads();  // keep next iter's pP writes after this iter's reads

        // ---- O += P V ----
        int koff0 = kb0 + quad * 8;
        int koff1 = kb0 + 32 + quad * 8;
        if (koff1 > 1560) koff1 = 1560;  // kt=24 tail: those P entries are 0
#pragma unroll
        for (int cg = 0; cg < 4; ++cg) {
            const unsigned short* vp = vbh + (size_t)(cg * 16 + l16) * 1568;
            bf16x8 v0 = ld_bf8(vp + koff0);
            bf16x8 v1 = ld_bf8(vp + koff1);
            Oacc[cg] = __builtin_amdgcn_mfma_f32_16x16x32_bf16(a_p0, v0, Oacc[cg], 0, 0, 0);
            Oacc[cg] = __builtin_amdgcn_mfma_f32_16x16x32_bf16(a_p1, v1, Oacc[cg], 0, 0, 0);
        }
    }

    // epilogue: O / l -> obf [b*1568+n][head*64+c] bf16
    int b_ = bh / 12;
    int head = bh - b_ * 12;
    unsigned short* ob = obf + (size_t)b_ * 1568 * 768 + head * 64;
#pragma unroll
    for (int r = 0; r < 4; ++r) {
        int gq = qt * 64 + wid * 16 + quad * 4 + r;
        if (gq < 1568) {
            float inv = 1.0f / l_i[r];
#pragma unroll
            for (int cg = 0; cg < 4; ++cg)
                ob[(size_t)gq * 768 + cg * 16 + l16] = f2bf(Oacc[cg][r] * inv);
        }
    }
}

// ---------------- GEMM3: out = O @ proj_w + proj_b (fp32 out) ----------------
__global__ __launch_bounds__(256) void k_proj(const unsigned short* __restrict__ obf,
                                              const unsigned short* __restrict__ w2t,
                                              const float* __restrict__ proj_b,
                                              float* __restrict__ out) {
    int lane = threadIdx.x & 63;
    int wid = threadIdx.x >> 6;
    int quad = lane >> 4;
    int l16 = lane & 15;
    int mbase = blockIdx.x * 64 + wid * 16;
    int nbase = blockIdx.y * 64;
    f32x4 acc[4] = {};
    const unsigned short* arow = obf + (size_t)(mbase + l16) * 768 + quad * 8;
    const unsigned short* brow = w2t + (size_t)(nbase + l16) * 768 + quad * 8;
    for (int ks = 0; ks < 24; ++ks) {
        bf16x8 a = ld_bf8(arow + ks * 32);
#pragma unroll
        for (int ng = 0; ng < 4; ++ng) {
            bf16x8 b = ld_bf8(brow + (size_t)ng * 16 * 768 + ks * 32);
            acc[ng] = __builtin_amdgcn_mfma_f32_16x16x32_bf16(a, b, acc[ng], 0, 0, 0);
        }
    }
#pragma unroll
    for (int ng = 0; ng < 4; ++ng) {
        int n = nbase + ng * 16 + l16;
        float bias = proj_b[n];
#pragma unroll
        for (int r = 0; r < 4; ++r) {
            int m = mbase + quad * 4 + r;
            out[(size_t)m * 768 + n] = acc[ng][r] + bias;
        }
    }
}

// ---------------- launch ----------------
extern "C" void kernel_launch(void* const* d_in, const int* in_sizes, int n_in,
                              void* d_out, int out_size, void* d_ws, size_t ws_size,
                              hipStream_t stream) {
    const float* x      = (const float*)d_in[0];
    const float* qkv_w  = (const float*)d_in[1];
    const float* qkv_b  = (const float*)d_in[2];
    const float* proj_w = (const float*)d_in[3];
    const float* proj_b = (const float*)d_in[4];
    const float* rd     = (const float*)d_in[5];
    const float* rh     = (const float*)d_in[6];
    const float* rw     = (const float*)d_in[7];
    float* out = (float*)d_out;

    char* ws = (char*)d_ws;
    size_t off = 0;
    auto alloc = [&](size_t bytes) {
        char* p = ws + off;
        off += (bytes + 255) & ~(size_t)255;
        return p;
    };
    unsigned short* xbf  = (unsigned short*)alloc((size_t)6272 * 768 * 2);   // reused as obf
    unsigned short* w1t  = (unsigned short*)alloc((size_t)2304 * 768 * 2);
    unsigned short* w2t  = (unsigned short*)alloc((size_t)768 * 768 * 2);
    unsigned short* Tbf  = (unsigned short*)alloc((size_t)80 * 64 * 2);
    unsigned short* qb   = (unsigned short*)alloc((size_t)48 * 1568 * 64 * 2);
    unsigned short* kbuf = (unsigned short*)alloc((size_t)48 * 1568 * 64 * 2);
    unsigned short* vtb  = (unsigned short*)alloc((size_t)48 * 64 * 1568 * 2);
    unsigned short* obf  = xbf;  // x is dead after k_qkv; attention output reuses it

    hipLaunchKernelGGL(k_cvt_x, dim3(4704), dim3(256), 0, stream, x, xbf, 1204224);
    hipLaunchKernelGGL(k_transpose, dim3(12, 36), dim3(256), 0, stream, qkv_w, w1t, 768, 2304);
    hipLaunchKernelGGL(k_transpose, dim3(12, 12), dim3(256), 0, stream, proj_w, w2t, 768, 768);
    hipLaunchKernelGGL(k_tables, dim3(20), dim3(256), 0, stream, rd, rh, rw, Tbf);
    hipLaunchKernelGGL(k_qkv, dim3(98, 36), dim3(256), 0, stream, xbf, w1t, qkv_b, qb, kbuf, vtb);
    hipLaunchKernelGGL(k_attn, dim3(25, 48), dim3(256), 0, stream, qb, kbuf, vtb, Tbf, obf);
    hipLaunchKernelGGL(k_proj, dim3(98, 12), dim3(256), 0, stream, obf, w2t, proj_b, out);
}